// Round 7
// baseline (130.157 us; speedup 1.0000x reference)
//
#include <hip/hip_runtime.h>
#include <math.h>

typedef float v4f __attribute__((ext_vector_type(4)));

#define NCOL4  28672       // W_proj row length in float4 (114688/4)
#define LAYER4 287744      // floats-per-layer / 4 (1150976/4) = 281*1024

// ws layout (floats)
#define OFF_PART 0                        // partials: 224*4*2*512 = 917,504 floats
#define OFF_ROWS (224 * 4 * 2 * 512)      // rows: 896 x 1024
// total: 1,835,008 floats = 7.3 MB

__device__ __forceinline__ float gelu_erf(float x) {
    return 0.5f * x * (1.0f + erff(x * 0.70710678118654752440f));
}

// K1: partial GEMV. Grid (224, 4): block (p, kq) covers k in [kq*96, kq*96+96)
// for the 512-col slice of p. 896 blocks -> ~3.5 blocks/CU, deep TLP on the
// HBM stream. part[((p*4+kq)*2+b)*512 + c] = sum_k cond[b][k]*W[k][p*512+c].
__global__ __launch_bounds__(512) void k_gemv(const float* __restrict__ cond,
                                              const float* __restrict__ W,
                                              float* __restrict__ part) {
    const int tid = threadIdx.x;
    const int p   = blockIdx.x;          // [0,224)
    const int kq  = blockIdx.y;          // [0,4)

    __shared__ float cs[768];            // full cond (2x384)
    __shared__ v4f   red[1024];          // k-split reduce (16 KB)

    cs[tid] = cond[tid];
    if (tid < 256) cs[512 + tid] = cond[512 + tid];
    __syncthreads();

    const int kres = tid >> 7;           // 0..3
    const int c4   = tid & 127;
    const int k0   = kq * 96 + kres;
    const v4f* __restrict__ Wp4 = (const v4f*)W + (size_t)k0 * NCOL4 + (size_t)p * 128 + c4;
    v4f a0 = {0.f, 0.f, 0.f, 0.f};
    v4f a1 = {0.f, 0.f, 0.f, 0.f};
#pragma unroll 8
    for (int i = 0; i < 24; ++i) {       // k = k0 + 4*i
        v4f w = Wp4[(size_t)i * (4 * NCOL4)];
        a0 += w * cs[k0 + 4 * i];
        a1 += w * cs[384 + k0 + 4 * i];
    }
    red[tid]       = a0;
    red[512 + tid] = a1;
    __syncthreads();
    if (tid < 256) {
        const int b = tid >> 7;
        const int c = tid & 127;
        const int o = b * 512 + c;
        v4f s = red[o] + red[o + 128] + red[o + 256] + red[o + 384];
        ((v4f*)part)[((size_t)(p * 4 + kq) * 2 + b) * 128 + c] = s;
    }
}

// K2: partial-reduce + dec1 + dec2 for 4 pe-rows (p pair x both b), one path
// per block. Grid (112, 2). Writes scaled rows[((p*2+b)*2+path)*1024].
__global__ __launch_bounds__(512) void k_dec(const float* __restrict__ part,
                                             const float* __restrict__ bproj,
                                             const float* __restrict__ WA1,
                                             const float* __restrict__ bA1,
                                             const float* __restrict__ WA2,
                                             const float* __restrict__ bA2,
                                             const float* __restrict__ WB1,
                                             const float* __restrict__ bB1,
                                             const float* __restrict__ WB2,
                                             const float* __restrict__ bB2,
                                             const float* __restrict__ scales,
                                             float* __restrict__ rows) {
    const int tid  = threadIdx.x;
    const int pp   = blockIdx.x;         // [0,112)
    const int path = blockIdx.y;         // 0=A, 1=B

    __shared__ float pe_s[4][512];       // rows r = (p_half<<1)|b
    __shared__ float h_s[4][256];

    // reduce partials + bias -> pe rows
    {
        const int r  = tid >> 7;
        const int c4 = tid & 127;
        const int p  = 2 * pp + (r >> 1);
        const int b  = r & 1;
        const v4f* __restrict__ part4 = (const v4f*)part;
        v4f s = ((const v4f*)bproj)[(size_t)p * 128 + c4];
#pragma unroll
        for (int kq = 0; kq < 4; ++kq)
            s += part4[((size_t)(p * 4 + kq) * 2 + b) * 128 + c4];
        ((v4f*)pe_s)[tid] = s;
    }
    __syncthreads();

    const float* __restrict__ W1 = path ? WB1 : WA1;
    const float* __restrict__ b1 = path ? bB1 : bA1;

    // dec1: h = gelu(pe @ W1 + b1) for rows {2half, 2half+1} (b=0,1 of p=2pp+half)
    {
        const int half = tid >> 8;
        const int j    = tid & 255;
        float a0 = 0.f, a1 = 0.f;
#pragma unroll 8
        for (int k = 0; k < 512; ++k) {
            float w = W1[k * 256 + j];
            a0 = fmaf(pe_s[2 * half][k], w, a0);
            a1 = fmaf(pe_s[2 * half + 1][k], w, a1);
        }
        float bb = b1[j];
        h_s[2 * half][j]     = gelu_erf(a0 + bb);
        h_s[2 * half + 1][j] = gelu_erf(a1 + bb);
    }
    __syncthreads();

    // dec2: row = (h @ W2 + b2) * scale
    {
        const int half = tid >> 8;
        const int j4   = tid & 255;
        const int p    = 2 * pp + half;
        const v4f* __restrict__ W2 = (const v4f*)(path ? WB2 : WA2);
        const v4f  b2 = ((const v4f*)(path ? bB2 : bA2))[j4];
        const float sc = scales[p * 2 + path];
        v4f a0 = {0.f, 0.f, 0.f, 0.f};
        v4f a1 = {0.f, 0.f, 0.f, 0.f};
#pragma unroll 4
        for (int k = 0; k < 256; ++k) {
            v4f w = W2[k * 256 + j4];
            a0 += h_s[2 * half][k] * w;
            a1 += h_s[2 * half + 1][k] * w;
        }
        v4f* __restrict__ rows4 = (v4f*)rows;
        const size_t rho0 = (size_t)(p * 2) * 2 + path;      // b=0
        rows4[(rho0)     * 256 + j4] = (a0 + b2) * sc;
        rows4[(rho0 + 2) * 256 + j4] = (a1 + b2) * sc;       // b=1
    }
}

// K3: balanced scatter (identical to round 6). blockIdx.y = b*32+l;
// blockIdx.x = chunk c in [0,281); thread writes f4 {c*1024+tid, +512}. nt stores.
__global__ __launch_bounds__(512) void k_scatter(const float* __restrict__ rows,
                                                 float* __restrict__ out) {
    const int yl = blockIdx.y;
    const int b  = yl >> 5;
    const int l  = yl & 31;
    const v4f* __restrict__ rows4 = (const v4f*)rows;
    v4f* __restrict__ out4 = (v4f*)out + (size_t)b * 9207808u + (size_t)l * LAYER4;

    const int f0 = blockIdx.x * 1024 + threadIdx.x;
#pragma unroll
    for (int u = 0; u < 2; ++u) {
        const int f = f0 + u * 512;
        int t, tstart, Asz = 16384;
        if (f < 106496) {
            if (f < 53248) { if (f < 32768) { t = 0; tstart = 0; }
                             else           { t = 1; tstart = 32768; } }
            else           { if (f < 73728) { t = 2; tstart = 53248; }
                             else           { t = 3; tstart = 73728; } }
        } else {
            if (f < 227328) { if (f < 166912) { t = 4; tstart = 106496; }
                              else            { t = 5; tstart = 166912; } }
            else            { t = 6; tstart = 227328; Asz = 44032; }
        }
        const int local = f - tstart;
        const int p = l * 7 + t;
        const v4f* __restrict__ Arow = rows4 + ((size_t)(p * 2 + b) * 2) * 256;
        v4f v;
        if (local < Asz) {
            int r = (t == 6) ? (int)(((unsigned)(local >> 6) * 1525u) >> 16)  // /43, exact x<1680
                             : (local >> 10);
            v = Arow[(r << 4) | (local & 15)];
        } else {
            int g = local - Asz;
            v = Arow[256 + ((((g >> 2) & 63) << 2) | (g & 3))];
        }
        __builtin_nontemporal_store(v, &out4[f]);
    }
}

extern "C" void kernel_launch(void* const* d_in, const int* in_sizes, int n_in,
                              void* d_out, int out_size, void* d_ws, size_t ws_size,
                              hipStream_t stream) {
    const float* cond   = (const float*)d_in[0];
    const float* Wp     = (const float*)d_in[1];
    const float* bproj  = (const float*)d_in[2];
    const float* WA1    = (const float*)d_in[3];
    const float* bA1    = (const float*)d_in[4];
    const float* WA2    = (const float*)d_in[5];
    const float* bA2    = (const float*)d_in[6];
    const float* WB1    = (const float*)d_in[7];
    const float* bB1    = (const float*)d_in[8];
    const float* WB2    = (const float*)d_in[9];
    const float* bB2    = (const float*)d_in[10];
    const float* scales = (const float*)d_in[11];
    float* out = (float*)d_out;
    float* ws  = (float*)d_ws;

    float* part = ws + OFF_PART;
    float* rows = ws + OFF_ROWS;

    hipLaunchKernelGGL(k_gemv,    dim3(224, 4),  dim3(512), 0, stream, cond, Wp, part);
    hipLaunchKernelGGL(k_dec,     dim3(112, 2),  dim3(512), 0, stream,
                       part, bproj, WA1, bA1, WA2, bA2, WB1, bB1, WB2, bB2, scales, rows);
    hipLaunchKernelGGL(k_scatter, dim3(281, 64), dim3(512), 0, stream, rows, out);
}